// Round 5
// baseline (378.662 us; speedup 1.0000x reference)
//
#include <hip/hip_runtime.h>
#include <math.h>

#define NATOM_FEAT 24   // IPSIN * NWAVE = 3*8
#define PORI 13
#define NW 8
#define HID 128
#define CH 64           // edges staged per LDS chunk
#define SCAN_T 1024
#define TA 32           // atoms per MLP block

// ---------------- CSR build ----------------
__global__ void csr_count(const int* __restrict__ nl, int* __restrict__ counts, int E)
{
    int e = blockIdx.x * blockDim.x + threadIdx.x;
    if (e < E) atomicAdd(&counts[nl[e]], 1);
}

__global__ void csr_scan(const int* __restrict__ counts, int* __restrict__ rowptr, int A)
{
    __shared__ int lds[SCAN_T];
    int tid = threadIdx.x;
    int chunk = (A + SCAN_T - 1) / SCAN_T;
    int base = tid * chunk;
    int own = 0;
    for (int i = 0; i < chunk; ++i) {
        int idx = base + i;
        if (idx < A) own += counts[idx];
    }
    lds[tid] = own;
    __syncthreads();
    for (int off = 1; off < SCAN_T; off <<= 1) {
        int v = (tid >= off) ? lds[tid - off] : 0;
        __syncthreads();
        lds[tid] += v;
        __syncthreads();
    }
    int running = lds[tid] - own;
    for (int i = 0; i < chunk; ++i) {
        int idx = base + i;
        if (idx < A) { rowptr[idx] = running; running += counts[idx]; }
    }
    if (tid == SCAN_T - 1) rowptr[A] = lds[SCAN_T - 1];
}

// scatter: geometry {dx,dy,dz,1.0} (16B) + neighbor id (4B) per slot
__global__ void csr_fill(const int* __restrict__ nl, const int* __restrict__ rowptr,
                         int* __restrict__ fill,
                         const float* __restrict__ cart,
                         const float* __restrict__ shifts,
                         float4* __restrict__ geom,
                         int* __restrict__ snb,
                         int E)
{
    int e = blockIdx.x * blockDim.x + threadIdx.x;
    if (e >= E) return;
    int c = nl[e];
    int n = nl[E + e];
    float dx = cart[3*c+0] - cart[3*n+0] - shifts[3*e+0];
    float dy = cart[3*c+1] - cart[3*n+1] - shifts[3*e+1];
    float dz = cart[3*c+2] - cart[3*n+2] - shifts[3*e+2];
    int ofs  = atomicAdd(&fill[c], 1);
    int slot = rowptr[c] + ofs;
    geom[slot] = make_float4(dx, dy, dz, 1.0f);
    snb[slot]  = n;
}

// slot-major: contiguous read of geom/snb, contiguous write of fc-folded gaussians
__global__ void gauss_k(const float4* __restrict__ geom,
                        const int* __restrict__ snb,
                        const int* __restrict__ species,
                        const float* __restrict__ g_rs,
                        const float* __restrict__ g_inta,
                        const float* __restrict__ g_par,
                        float4* __restrict__ gauss,   // [2E]
                        int E)
{
    __shared__ float s_rs[32], s_in[32], s_pa[32];
    int tid = threadIdx.x;
    if (tid < 32) {
        s_rs[tid] = g_rs[tid];
        s_in[tid] = g_inta[tid];
        s_pa[tid] = g_par[tid];
    }
    __syncthreads();
    int s = blockIdx.x * blockDim.x + tid;
    if (s >= E) return;
    float4 G = geom[s];
    float r = sqrtf(G.x*G.x + G.y*G.y + G.z*G.z);
    float fcb = 0.5f * cosf(r * 0.6283185307179586f) + 0.5f;   // pi/5
    float fc  = fcb * fcb;
    int sb = species[snb[s]] * NW;
    float g[NW];
    #pragma unroll
    for (int w = 0; w < NW; ++w) {
        float dr = r - s_rs[sb + w];
        g[w] = __expf(-s_in[sb + w] * dr * dr) * s_pa[sb + w] * fc;
    }
    gauss[2*s+0] = make_float4(g[0], g[1], g[2], g[3]);
    gauss[2*s+1] = make_float4(g[4], g[5], g[6], g[7]);
}

// ---------------- fused per-atom pass: gather precomputed edges -> orbital -> density ----------------
template<bool HASOUT>
__global__ __launch_bounds__(128)
void atom_pass(const float4* __restrict__ geom,
               const float4* __restrict__ gauss,
               const int* __restrict__ snb,
               const int* __restrict__ rowptr,
               const float* __restrict__ outp,   // [A,24] if HASOUT
               float* __restrict__ dens,         // [A,24]
               int A)
{
    __shared__ float4 ls_gm[CH];
    __shared__ float4 ls_g[CH][2];
    __shared__ float  ls_o[CH][NATOM_FEAT];
    __shared__ float  orb_s[PORI][NW];

    int tid = threadIdx.x;
    int a = blockIdx.x;
    int s0 = rowptr[a], s1 = rowptr[a+1];

    int f = tid;                     // f = p*8 + w, valid for f < 104
    int p = f >> 3, w = f & 7;
    int ip = (p == 0) ? 0 : ((p < 4) ? 1 : 2);
    int bi1 = (p == 0) ? -1 : ((p < 4) ? (p - 1) : (p - 4) / 3);
    int bi2 = (p < 4) ? -1 : (p - 4) % 3;
    float acc = 0.0f;

    for (int s = s0; s < s1; s += CH) {
        int m = min(CH, s1 - s);
        if (tid < m) {
            ls_gm[tid]   = geom[s + tid];
            ls_g[tid][0] = gauss[2*(s + tid) + 0];
            ls_g[tid][1] = gauss[2*(s + tid) + 1];
        }
        if (HASOUT) {
            for (int idx = tid; idx < m * NATOM_FEAT; idx += 128) {
                int j = idx / NATOM_FEAT;         // magic-mul, compile-time const
                int c = idx - j * NATOM_FEAT;
                ls_o[j][c] = outp[(size_t)snb[s + j] * NATOM_FEAT + c];
            }
        }
        __syncthreads();
        if (f < PORI * NW) {
            for (int j = 0; j < m; ++j) {
                float4 G = ls_gm[j];
                float gg = ((const float*)ls_g[j])[w];
                float v1 = (bi1 == 0) ? G.x : ((bi1 == 1) ? G.y : ((bi1 == 2) ? G.z : 1.0f));
                float v2 = (bi2 == 0) ? G.x : ((bi2 == 1) ? G.y : ((bi2 == 2) ? G.z : 1.0f));
                float v = v1 * v2 * gg;
                if (HASOUT) v *= ls_o[j][ip * NW + w];
                acc += v;
            }
        }
        __syncthreads();
    }

    if (f < PORI * NW) orb_s[p][w] = acc * acc;
    __syncthreads();
    if (tid < NATOM_FEAT) {
        int i = tid >> 3, ww = tid & 7;
        float sum;
        if (i == 0) {
            sum = orb_s[0][ww];
        } else if (i == 1) {
            sum = orb_s[1][ww] + orb_s[2][ww] + orb_s[3][ww];
        } else {
            sum = 0.0f;
            #pragma unroll
            for (int q = 4; q < PORI; ++q) sum += orb_s[q][ww];
        }
        dens[(size_t)a * NATOM_FEAT + tid] = sum;
    }
}

// ---------------- MLP: outp = tanh(dens @ w1 + b1) @ w2 + b2 ; tiled, 32 atoms/block ----------------
__global__ __launch_bounds__(256)
void mlp_k(const float* __restrict__ dens,
           const float* __restrict__ w1, const float* __restrict__ b1,
           const float* __restrict__ w2, const float* __restrict__ b2,
           float* __restrict__ outp, int A)
{
    __shared__ float d_s[TA][NATOM_FEAT];    // 32x24
    __shared__ float t_s[TA][HID + 1];       // 32x129 (pad kills phase-C bank conflict)
    int tid = threadIdx.x;
    int a0 = blockIdx.x * TA;

    for (int i = tid; i < TA * NATOM_FEAT; i += 256) {
        int gidx = a0 * NATOM_FEAT + i;
        ((float*)d_s)[i] = (gidx < A * NATOM_FEAT) ? dens[gidx] : 0.0f;
    }
    __syncthreads();

    #pragma unroll
    for (int k = 0; k < TA * HID / 256; ++k) {
        int task = tid + k * 256;
        int a = task >> 7;
        int h = task & (HID - 1);
        float acc = b1[h];
        #pragma unroll
        for (int j = 0; j < NATOM_FEAT; ++j) acc += d_s[a][j] * w1[j * HID + h];
        float e = __expf(2.0f * acc);
        t_s[a][h] = 1.0f - 2.0f / (e + 1.0f);   // tanh, saturates correctly
    }
    __syncthreads();

    #pragma unroll
    for (int k = 0; k < 3; ++k) {
        int task = tid + k * 256;
        int a = task / NATOM_FEAT;
        int j = task - a * NATOM_FEAT;
        float o = b2[j];
        #pragma unroll 8
        for (int h = 0; h < HID; ++h) o += t_s[a][h] * w2[h * NATOM_FEAT + j];
        int gidx = a0 * NATOM_FEAT + task;
        if (gidx < A * NATOM_FEAT) outp[gidx] = o;
    }
}

extern "C" void kernel_launch(void* const* d_in, const int* in_sizes, int n_in,
                              void* d_out, int out_size, void* d_ws, size_t ws_size,
                              hipStream_t stream)
{
    const float* cart    = (const float*)d_in[0];
    const int*   nl      = (const int*)d_in[1];
    const float* shifts  = (const float*)d_in[2];
    const int*   species = (const int*)d_in[3];
    const float* rs      = (const float*)d_in[4];
    const float* inta    = (const float*)d_in[5];
    const float* params  = (const float*)d_in[6];
    const float* w1_0 = (const float*)d_in[7];
    const float* b1_0 = (const float*)d_in[8];
    const float* w2_0 = (const float*)d_in[9];
    const float* b2_0 = (const float*)d_in[10];
    const float* w1_1 = (const float*)d_in[11];
    const float* b1_1 = (const float*)d_in[12];
    const float* w2_1 = (const float*)d_in[13];
    const float* b2_1 = (const float*)d_in[14];

    const int A = in_sizes[0] / 3;
    const int E = in_sizes[1] / 2;

    // workspace layout — 16B-aligned arrays first
    char* ws = (char*)d_ws;
    float4* geom  = (float4*)ws;              ws += (size_t)E * 16;
    float4* gauss = (float4*)ws;              ws += (size_t)E * 32;
    int*   snb    = (int*)ws;                 ws += (size_t)E * 4;
    int*   counts = (int*)ws;                 ws += (size_t)A * 4;
    int*   fill   = (int*)ws;                 ws += (size_t)A * 4;
    int*   rowptr = (int*)ws;                 ws += (size_t)(A + 1) * 4;
    float* dens   = (float*)ws;               ws += (size_t)A * NATOM_FEAT * 4;
    float* outp   = (float*)ws;               ws += (size_t)A * NATOM_FEAT * 4;
    float* dout   = (float*)d_out;

    const int BLK = 256;
    const int gridE = (E + BLK - 1) / BLK;
    const int gridM = (A + TA - 1) / TA;

    // ---- CSR build + per-edge precompute (once) ----
    hipMemsetAsync(counts, 0, (size_t)A * 4, stream);
    hipMemsetAsync(fill,   0, (size_t)A * 4, stream);
    csr_count<<<gridE, BLK, 0, stream>>>(nl, counts, E);
    csr_scan<<<1, SCAN_T, 0, stream>>>(counts, rowptr, A);
    csr_fill<<<gridE, BLK, 0, stream>>>(nl, rowptr, fill, cart, shifts, geom, snb, E);
    gauss_k<<<gridE, BLK, 0, stream>>>(geom, snb, species, rs, inta, params, gauss, E);

    // ---- pass 0 ----
    atom_pass<false><<<A, 128, 0, stream>>>(geom, gauss, snb, rowptr, nullptr, dens, A);
    // ---- pass 1 ----
    mlp_k<<<gridM, 256, 0, stream>>>(dens, w1_0, b1_0, w2_0, b2_0, outp, A);
    atom_pass<true><<<A, 128, 0, stream>>>(geom, gauss, snb, rowptr, outp, dens, A);
    // ---- pass 2 (final -> d_out) ----
    mlp_k<<<gridM, 256, 0, stream>>>(dens, w1_1, b1_1, w2_1, b2_1, outp, A);
    atom_pass<true><<<A, 128, 0, stream>>>(geom, gauss, snb, rowptr, outp, dout, A);
}

// Round 6
// 238.850 us; speedup vs baseline: 1.5854x; 1.5854x over previous
//
#include <hip/hip_runtime.h>
#include <math.h>

#define NATOM_FEAT 24   // IPSIN * NWAVE = 3*8
#define PORI 13
#define NW 8
#define HID 128
#define CH 64           // edges staged per LDS chunk
#define SCAN_T 1024
#define TA 32           // atoms per MLP block

// ---------------- CSR build ----------------
__global__ void csr_count(const int* __restrict__ nl, int* __restrict__ counts, int E)
{
    int e = blockIdx.x * blockDim.x + threadIdx.x;
    if (e < E) atomicAdd(&counts[nl[e]], 1);
}

__global__ void csr_scan(const int* __restrict__ counts, int* __restrict__ rowptr, int A)
{
    __shared__ int lds[SCAN_T];
    int tid = threadIdx.x;
    int chunk = (A + SCAN_T - 1) / SCAN_T;
    int base = tid * chunk;
    int own = 0;
    for (int i = 0; i < chunk; ++i) {
        int idx = base + i;
        if (idx < A) own += counts[idx];
    }
    lds[tid] = own;
    __syncthreads();
    for (int off = 1; off < SCAN_T; off <<= 1) {
        int v = (tid >= off) ? lds[tid - off] : 0;
        __syncthreads();
        lds[tid] += v;
        __syncthreads();
    }
    int running = lds[tid] - own;
    for (int i = 0; i < chunk; ++i) {
        int idx = base + i;
        if (idx < A) { rowptr[idx] = running; running += counts[idx]; }
    }
    if (tid == SCAN_T - 1) rowptr[A] = lds[SCAN_T - 1];
}

// scatter: geometry {dx,dy,dz,1.0} (16B) + neighbor id (4B) per slot
__global__ void csr_fill(const int* __restrict__ nl, const int* __restrict__ rowptr,
                         int* __restrict__ fill,
                         const float* __restrict__ cart,
                         const float* __restrict__ shifts,
                         float4* __restrict__ geom,
                         int* __restrict__ snb,
                         int E)
{
    int e = blockIdx.x * blockDim.x + threadIdx.x;
    if (e >= E) return;
    int c = nl[e];
    int n = nl[E + e];
    float dx = cart[3*c+0] - cart[3*n+0] - shifts[3*e+0];
    float dy = cart[3*c+1] - cart[3*n+1] - shifts[3*e+1];
    float dz = cart[3*c+2] - cart[3*n+2] - shifts[3*e+2];
    int ofs  = atomicAdd(&fill[c], 1);
    int slot = rowptr[c] + ofs;
    geom[slot] = make_float4(dx, dy, dz, 1.0f);
    snb[slot]  = n;
}

// slot-major: contiguous read of geom/snb, contiguous write of fc-folded gaussians
__global__ void gauss_k(const float4* __restrict__ geom,
                        const int* __restrict__ snb,
                        const int* __restrict__ species,
                        const float* __restrict__ g_rs,
                        const float* __restrict__ g_inta,
                        const float* __restrict__ g_par,
                        float4* __restrict__ gauss,   // [2E] = [E][8] floats
                        int E)
{
    __shared__ float s_rs[32], s_in[32], s_pa[32];
    int tid = threadIdx.x;
    if (tid < 32) {
        s_rs[tid] = g_rs[tid];
        s_in[tid] = g_inta[tid];
        s_pa[tid] = g_par[tid];
    }
    __syncthreads();
    int s = blockIdx.x * blockDim.x + tid;
    if (s >= E) return;
    float4 G = geom[s];
    float r = sqrtf(G.x*G.x + G.y*G.y + G.z*G.z);
    float fcb = 0.5f * cosf(r * 0.6283185307179586f) + 0.5f;   // pi/5
    float fc  = fcb * fcb;
    int sb = species[snb[s]] * NW;
    float g[NW];
    #pragma unroll
    for (int w = 0; w < NW; ++w) {
        float dr = r - s_rs[sb + w];
        g[w] = __expf(-s_in[sb + w] * dr * dr) * s_pa[sb + w] * fc;
    }
    gauss[2*s+0] = make_float4(g[0], g[1], g[2], g[3]);
    gauss[2*s+1] = make_float4(g[4], g[5], g[6], g[7]);
}

// ---------------- fused per-atom pass ----------------
// Inner loop is the algebraic minimum: acc += ls_ang[j][p] * ls_og[j][ip*8+w]
template<bool HASOUT>
__global__ __launch_bounds__(128)
void atom_pass(const float4* __restrict__ geom,
               const float* __restrict__ gauss8,   // [E*8], fc-folded
               const int* __restrict__ snb,
               const int* __restrict__ rowptr,
               const float* __restrict__ outp,     // [A,24] if HASOUT
               float* __restrict__ dens,           // [A,24]
               int A)
{
    __shared__ float ls_ang[CH][PORI];        // stride 13 (odd) -> conflict-free
    __shared__ float ls_og[CH][NATOM_FEAT];
    __shared__ float orb_s[PORI * NW];

    int tid = threadIdx.x;
    int a = blockIdx.x;
    int s0 = rowptr[a], s1 = rowptr[a+1];

    int f = tid;                     // f = p*8 + w, valid for f < 104
    int p = f >> 3, w = f & 7;
    int ip = (p == 0) ? 0 : ((p < 4) ? 1 : 2);
    int ogidx = ip * NW + w;
    float acc = 0.0f;

    for (int s = s0; s < s1; s += CH) {
        int m = min(CH, s1 - s);
        if (tid < m) {
            float4 G = geom[s + tid];
            float ax = G.x, ay = G.y, az = G.z;
            ls_ang[tid][0]  = 1.0f;
            ls_ang[tid][1]  = ax;    ls_ang[tid][2]  = ay;    ls_ang[tid][3]  = az;
            ls_ang[tid][4]  = ax*ax; ls_ang[tid][5]  = ax*ay; ls_ang[tid][6]  = ax*az;
            ls_ang[tid][7]  = ay*ax; ls_ang[tid][8]  = ay*ay; ls_ang[tid][9]  = ay*az;
            ls_ang[tid][10] = az*ax; ls_ang[tid][11] = az*ay; ls_ang[tid][12] = az*az;
        }
        for (int idx = tid; idx < m * NATOM_FEAT; idx += 128) {
            int j = idx / NATOM_FEAT;          // const divisor -> magic mul
            int c = idx - j * NATOM_FEAT;
            float gg = gauss8[(size_t)(s + j) * NW + (c & 7)];
            if (HASOUT) gg *= outp[(size_t)snb[s + j] * NATOM_FEAT + c];
            ls_og[j][c] = gg;
        }
        __syncthreads();
        if (f < PORI * NW) {
            #pragma unroll 4
            for (int j = 0; j < m; ++j)
                acc += ls_ang[j][p] * ls_og[j][ogidx];
        }
        __syncthreads();
    }

    if (f < PORI * NW) orb_s[f] = acc * acc;
    __syncthreads();
    if (tid < NATOM_FEAT) {
        int i = tid >> 3, ww = tid & 7;
        float sum;
        if (i == 0) {
            sum = orb_s[ww];
        } else if (i == 1) {
            sum = orb_s[NW + ww] + orb_s[2*NW + ww] + orb_s[3*NW + ww];
        } else {
            sum = 0.0f;
            #pragma unroll
            for (int q = 4; q < PORI; ++q) sum += orb_s[q*NW + ww];
        }
        dens[(size_t)a * NATOM_FEAT + tid] = sum;
    }
}

// ---------------- MLP: outp = tanh(dens @ w1 + b1) @ w2 + b2 ; tiled, 32 atoms/block ----------------
__global__ __launch_bounds__(256)
void mlp_k(const float* __restrict__ dens,
           const float* __restrict__ w1, const float* __restrict__ b1,
           const float* __restrict__ w2, const float* __restrict__ b2,
           float* __restrict__ outp, int A)
{
    __shared__ float d_s[TA][NATOM_FEAT];    // 32x24
    __shared__ float t_s[TA][HID + 1];       // 32x129 (pad kills phase-C bank conflict)
    int tid = threadIdx.x;
    int a0 = blockIdx.x * TA;

    for (int i = tid; i < TA * NATOM_FEAT; i += 256) {
        int gidx = a0 * NATOM_FEAT + i;
        ((float*)d_s)[i] = (gidx < A * NATOM_FEAT) ? dens[gidx] : 0.0f;
    }
    __syncthreads();

    #pragma unroll
    for (int k = 0; k < TA * HID / 256; ++k) {
        int task = tid + k * 256;
        int a = task >> 7;
        int h = task & (HID - 1);
        float acc = b1[h];
        #pragma unroll
        for (int j = 0; j < NATOM_FEAT; ++j) acc += d_s[a][j] * w1[j * HID + h];
        float e = __expf(2.0f * acc);
        t_s[a][h] = 1.0f - 2.0f / (e + 1.0f);   // tanh, saturates correctly
    }
    __syncthreads();

    #pragma unroll
    for (int k = 0; k < 3; ++k) {
        int task = tid + k * 256;
        int a = task / NATOM_FEAT;
        int j = task - a * NATOM_FEAT;
        float o = b2[j];
        #pragma unroll 8
        for (int h = 0; h < HID; ++h) o += t_s[a][h] * w2[h * NATOM_FEAT + j];
        int gidx = a0 * NATOM_FEAT + task;
        if (gidx < A * NATOM_FEAT) outp[gidx] = o;
    }
}

extern "C" void kernel_launch(void* const* d_in, const int* in_sizes, int n_in,
                              void* d_out, int out_size, void* d_ws, size_t ws_size,
                              hipStream_t stream)
{
    const float* cart    = (const float*)d_in[0];
    const int*   nl      = (const int*)d_in[1];
    const float* shifts  = (const float*)d_in[2];
    const int*   species = (const int*)d_in[3];
    const float* rs      = (const float*)d_in[4];
    const float* inta    = (const float*)d_in[5];
    const float* params  = (const float*)d_in[6];
    const float* w1_0 = (const float*)d_in[7];
    const float* b1_0 = (const float*)d_in[8];
    const float* w2_0 = (const float*)d_in[9];
    const float* b2_0 = (const float*)d_in[10];
    const float* w1_1 = (const float*)d_in[11];
    const float* b1_1 = (const float*)d_in[12];
    const float* w2_1 = (const float*)d_in[13];
    const float* b2_1 = (const float*)d_in[14];

    const int A = in_sizes[0] / 3;
    const int E = in_sizes[1] / 2;

    // workspace layout — 16B-aligned arrays first
    char* ws = (char*)d_ws;
    float4* geom  = (float4*)ws;              ws += (size_t)E * 16;
    float4* gauss = (float4*)ws;              ws += (size_t)E * 32;
    int*   snb    = (int*)ws;                 ws += (size_t)E * 4;
    int*   counts = (int*)ws;                 ws += (size_t)A * 4;
    int*   fill   = (int*)ws;                 ws += (size_t)A * 4;
    int*   rowptr = (int*)ws;                 ws += (size_t)(A + 1) * 4;
    float* dens   = (float*)ws;               ws += (size_t)A * NATOM_FEAT * 4;
    float* outp   = (float*)ws;               ws += (size_t)A * NATOM_FEAT * 4;
    float* dout   = (float*)d_out;

    const int BLK = 256;
    const int gridE = (E + BLK - 1) / BLK;
    const int gridM = (A + TA - 1) / TA;

    // ---- CSR build + per-edge precompute (once) ----
    hipMemsetAsync(counts, 0, (size_t)A * 4, stream);
    hipMemsetAsync(fill,   0, (size_t)A * 4, stream);
    csr_count<<<gridE, BLK, 0, stream>>>(nl, counts, E);
    csr_scan<<<1, SCAN_T, 0, stream>>>(counts, rowptr, A);
    csr_fill<<<gridE, BLK, 0, stream>>>(nl, rowptr, fill, cart, shifts, geom, snb, E);
    gauss_k<<<gridE, BLK, 0, stream>>>(geom, snb, species, rs, inta, params, gauss, E);

    // ---- pass 0 ----
    atom_pass<false><<<A, 128, 0, stream>>>(geom, (const float*)gauss, snb, rowptr, nullptr, dens, A);
    // ---- pass 1 ----
    mlp_k<<<gridM, 256, 0, stream>>>(dens, w1_0, b1_0, w2_0, b2_0, outp, A);
    atom_pass<true><<<A, 128, 0, stream>>>(geom, (const float*)gauss, snb, rowptr, outp, dens, A);
    // ---- pass 2 (final -> d_out) ----
    mlp_k<<<gridM, 256, 0, stream>>>(dens, w1_1, b1_1, w2_1, b2_1, outp, A);
    atom_pass<true><<<A, 128, 0, stream>>>(geom, (const float*)gauss, snb, rowptr, outp, dout, A);
}

// Round 7
// 206.452 us; speedup vs baseline: 1.8341x; 1.1569x over previous
//
#include <hip/hip_runtime.h>
#include <math.h>

#define NATOM_FEAT 24   // IPSIN * NWAVE = 3*8
#define PORI 13
#define NW 8
#define HID 128
#define CH 64           // edges staged per LDS chunk
#define SCAN_T 1024
#define TA 8            // atoms per MLP block

__global__ void zero_k(int* __restrict__ p, int n)
{
    int i = blockIdx.x * blockDim.x + threadIdx.x;
    if (i < n) p[i] = 0;
}

// ---------------- CSR build ----------------
__global__ void csr_count(const int* __restrict__ nl, int* __restrict__ counts, int E)
{
    int e = blockIdx.x * blockDim.x + threadIdx.x;
    if (e < E) atomicAdd(&counts[nl[e]], 1);
}

// scan counts -> rowptr, and re-zero counts (so csr_fill can reuse it as cursor)
__global__ void csr_scan(int* __restrict__ counts, int* __restrict__ rowptr, int A)
{
    __shared__ int lds[SCAN_T];
    int tid = threadIdx.x;
    int chunk = (A + SCAN_T - 1) / SCAN_T;
    int base = tid * chunk;
    int own = 0;
    for (int i = 0; i < chunk; ++i) {
        int idx = base + i;
        if (idx < A) own += counts[idx];
    }
    lds[tid] = own;
    __syncthreads();
    for (int off = 1; off < SCAN_T; off <<= 1) {
        int v = (tid >= off) ? lds[tid - off] : 0;
        __syncthreads();
        lds[tid] += v;
        __syncthreads();
    }
    int running = lds[tid] - own;
    for (int i = 0; i < chunk; ++i) {
        int idx = base + i;
        if (idx < A) {
            rowptr[idx] = running;
            running += counts[idx];
            counts[idx] = 0;           // reset for reuse as fill cursor
        }
    }
    if (tid == SCAN_T - 1) rowptr[A] = lds[SCAN_T - 1];
}

// scatter: geometry {dx,dy,dz,1.0} (16B) + neighbor id (4B) per slot; cursor = counts
__global__ void csr_fill(const int* __restrict__ nl, const int* __restrict__ rowptr,
                         int* __restrict__ cursor,
                         const float* __restrict__ cart,
                         const float* __restrict__ shifts,
                         float4* __restrict__ geom,
                         int* __restrict__ snb,
                         int E)
{
    int e = blockIdx.x * blockDim.x + threadIdx.x;
    if (e >= E) return;
    int c = nl[e];
    int n = nl[E + e];
    float dx = cart[3*c+0] - cart[3*n+0] - shifts[3*e+0];
    float dy = cart[3*c+1] - cart[3*n+1] - shifts[3*e+1];
    float dz = cart[3*c+2] - cart[3*n+2] - shifts[3*e+2];
    int ofs  = atomicAdd(&cursor[c], 1);
    int slot = rowptr[c] + ofs;
    geom[slot] = make_float4(dx, dy, dz, 1.0f);
    snb[slot]  = n;
}

// slot-major: contiguous read of geom/snb, contiguous write of fc-folded gaussians
__global__ void gauss_k(const float4* __restrict__ geom,
                        const int* __restrict__ snb,
                        const int* __restrict__ species,
                        const float* __restrict__ g_rs,
                        const float* __restrict__ g_inta,
                        const float* __restrict__ g_par,
                        float4* __restrict__ gauss,   // [2E] = [E][8] floats
                        int E)
{
    __shared__ float s_rs[32], s_in[32], s_pa[32];
    int tid = threadIdx.x;
    if (tid < 32) {
        s_rs[tid] = g_rs[tid];
        s_in[tid] = g_inta[tid];
        s_pa[tid] = g_par[tid];
    }
    __syncthreads();
    int s = blockIdx.x * blockDim.x + tid;
    if (s >= E) return;
    float4 G = geom[s];
    float r = sqrtf(G.x*G.x + G.y*G.y + G.z*G.z);
    float fcb = 0.5f * cosf(r * 0.6283185307179586f) + 0.5f;   // pi/5
    float fc  = fcb * fcb;
    int sb = species[snb[s]] * NW;
    float g[NW];
    #pragma unroll
    for (int w = 0; w < NW; ++w) {
        float dr = r - s_rs[sb + w];
        g[w] = __expf(-s_in[sb + w] * dr * dr) * s_pa[sb + w] * fc;
    }
    gauss[2*s+0] = make_float4(g[0], g[1], g[2], g[3]);
    gauss[2*s+1] = make_float4(g[4], g[5], g[6], g[7]);
}

// ---------------- fused per-atom pass ----------------
template<bool HASOUT>
__global__ __launch_bounds__(128)
void atom_pass(const float4* __restrict__ geom,
               const float* __restrict__ gauss8,   // [E*8], fc-folded
               const int* __restrict__ snb,
               const int* __restrict__ rowptr,
               const float* __restrict__ outp,     // [A,24] if HASOUT
               float* __restrict__ dens,           // [A,24]
               int A)
{
    __shared__ float ls_ang[CH][PORI];        // stride 13 (odd) -> conflict-free
    __shared__ float ls_og[CH][NATOM_FEAT];
    __shared__ float orb_s[PORI * NW];

    int tid = threadIdx.x;
    int a = blockIdx.x;
    int s0 = rowptr[a], s1 = rowptr[a+1];

    int f = tid;                     // f = p*8 + w, valid for f < 104
    int p = f >> 3, w = f & 7;
    int ip = (p == 0) ? 0 : ((p < 4) ? 1 : 2);
    int ogidx = ip * NW + w;
    float acc = 0.0f;

    for (int s = s0; s < s1; s += CH) {
        int m = min(CH, s1 - s);
        if (tid < m) {
            float4 G = geom[s + tid];
            float ax = G.x, ay = G.y, az = G.z;
            ls_ang[tid][0]  = 1.0f;
            ls_ang[tid][1]  = ax;    ls_ang[tid][2]  = ay;    ls_ang[tid][3]  = az;
            ls_ang[tid][4]  = ax*ax; ls_ang[tid][5]  = ax*ay; ls_ang[tid][6]  = ax*az;
            ls_ang[tid][7]  = ay*ax; ls_ang[tid][8]  = ay*ay; ls_ang[tid][9]  = ay*az;
            ls_ang[tid][10] = az*ax; ls_ang[tid][11] = az*ay; ls_ang[tid][12] = az*az;
        }
        for (int idx = tid; idx < m * NATOM_FEAT; idx += 128) {
            int j = idx / NATOM_FEAT;          // const divisor -> magic mul
            int c = idx - j * NATOM_FEAT;
            float gg = gauss8[(size_t)(s + j) * NW + (c & 7)];
            if (HASOUT) gg *= outp[(size_t)snb[s + j] * NATOM_FEAT + c];
            ls_og[j][c] = gg;
        }
        __syncthreads();
        if (f < PORI * NW) {
            #pragma unroll 4
            for (int j = 0; j < m; ++j)
                acc += ls_ang[j][p] * ls_og[j][ogidx];
        }
        __syncthreads();
    }

    if (f < PORI * NW) orb_s[f] = acc * acc;
    __syncthreads();
    if (tid < NATOM_FEAT) {
        int i = tid >> 3, ww = tid & 7;
        float sum;
        if (i == 0) {
            sum = orb_s[ww];
        } else if (i == 1) {
            sum = orb_s[NW + ww] + orb_s[2*NW + ww] + orb_s[3*NW + ww];
        } else {
            sum = 0.0f;
            #pragma unroll
            for (int q = 4; q < PORI; ++q) sum += orb_s[q*NW + ww];
        }
        dens[(size_t)a * NATOM_FEAT + tid] = sum;
    }
}

// ---------------- MLP: outp = tanh(dens @ w1 + b1) @ w2 + b2 ----------------
// TA=8 atoms/block (2500 blocks), all weights staged in LDS, conflict-free reads.
__global__ __launch_bounds__(256)
void mlp_k(const float* __restrict__ dens,
           const float* __restrict__ w1, const float* __restrict__ b1,
           const float* __restrict__ w2, const float* __restrict__ b2,
           float* __restrict__ outp, int A)
{
    __shared__ float w1s[NATOM_FEAT * HID];   // [j][h] natural, 12KB
    __shared__ float w2s[HID * NATOM_FEAT];   // [h][j] natural, 12KB
    __shared__ float b1s[HID];
    __shared__ float b2s[NATOM_FEAT];
    __shared__ float d_s[TA][NATOM_FEAT];     // 8x24
    __shared__ float t_s[TA][HID + 1];        // 8x129

    int tid = threadIdx.x;
    int a0 = blockIdx.x * TA;

    // stage weights (coalesced float4: 3072 floats each = 768 float4)
    {
        const float4* w1v = (const float4*)w1;
        const float4* w2v = (const float4*)w2;
        float4* w1sv = (float4*)w1s;
        float4* w2sv = (float4*)w2s;
        #pragma unroll
        for (int k = 0; k < 3; ++k) {
            int i = tid + k * 256;
            w1sv[i] = w1v[i];
            w2sv[i] = w2v[i];
        }
        if (tid < HID) b1s[tid] = b1[tid];
        else if (tid < HID + NATOM_FEAT) b2s[tid - HID] = b2[tid - HID];
    }
    // stage dens tile (192 floats)
    if (tid < TA * NATOM_FEAT) {
        int gidx = a0 * NATOM_FEAT + tid;
        ((float*)d_s)[tid] = (gidx < A * NATOM_FEAT) ? dens[gidx] : 0.0f;
    }
    __syncthreads();

    // phase B: (a,h) tasks = 8*128 = 1024; lanes consecutive h -> w1s stride-1, d_s broadcast
    #pragma unroll
    for (int k = 0; k < TA * HID / 256; ++k) {
        int task = tid + k * 256;
        int a = task >> 7;
        int h = task & (HID - 1);
        float acc = b1s[h];
        #pragma unroll
        for (int j = 0; j < NATOM_FEAT; ++j) acc += d_s[a][j] * w1s[j * HID + h];
        float e = __expf(2.0f * acc);
        t_s[a][h] = 1.0f - 2.0f / (e + 1.0f);   // tanh, saturates correctly
    }
    __syncthreads();

    // phase C: (a,j) tasks = 8*24 = 192; lanes consecutive j -> w2s stride-1, t_s broadcast
    if (tid < TA * NATOM_FEAT) {
        int a = tid / NATOM_FEAT;
        int j = tid - a * NATOM_FEAT;
        float o = b2s[j];
        #pragma unroll 8
        for (int h = 0; h < HID; ++h) o += t_s[a][h] * w2s[h * NATOM_FEAT + j];
        int gidx = a0 * NATOM_FEAT + tid;
        if (gidx < A * NATOM_FEAT) outp[gidx] = o;
    }
}

extern "C" void kernel_launch(void* const* d_in, const int* in_sizes, int n_in,
                              void* d_out, int out_size, void* d_ws, size_t ws_size,
                              hipStream_t stream)
{
    const float* cart    = (const float*)d_in[0];
    const int*   nl      = (const int*)d_in[1];
    const float* shifts  = (const float*)d_in[2];
    const int*   species = (const int*)d_in[3];
    const float* rs      = (const float*)d_in[4];
    const float* inta    = (const float*)d_in[5];
    const float* params  = (const float*)d_in[6];
    const float* w1_0 = (const float*)d_in[7];
    const float* b1_0 = (const float*)d_in[8];
    const float* w2_0 = (const float*)d_in[9];
    const float* b2_0 = (const float*)d_in[10];
    const float* w1_1 = (const float*)d_in[11];
    const float* b1_1 = (const float*)d_in[12];
    const float* w2_1 = (const float*)d_in[13];
    const float* b2_1 = (const float*)d_in[14];

    const int A = in_sizes[0] / 3;
    const int E = in_sizes[1] / 2;

    // workspace layout — 16B-aligned arrays first
    char* ws = (char*)d_ws;
    float4* geom  = (float4*)ws;              ws += (size_t)E * 16;
    float4* gauss = (float4*)ws;              ws += (size_t)E * 32;
    int*   snb    = (int*)ws;                 ws += (size_t)E * 4;
    int*   counts = (int*)ws;                 ws += (size_t)A * 4;
    int*   rowptr = (int*)ws;                 ws += (size_t)(A + 1) * 4;
    float* dens   = (float*)ws;               ws += (size_t)A * NATOM_FEAT * 4;
    float* outp   = (float*)ws;               ws += (size_t)A * NATOM_FEAT * 4;
    float* dout   = (float*)d_out;

    const int BLK = 256;
    const int gridE = (E + BLK - 1) / BLK;
    const int gridA = (A + BLK - 1) / BLK;
    const int gridM = (A + TA - 1) / TA;

    // ---- CSR build + per-edge precompute (once) ----
    zero_k<<<gridA, BLK, 0, stream>>>(counts, A);
    csr_count<<<gridE, BLK, 0, stream>>>(nl, counts, E);
    csr_scan<<<1, SCAN_T, 0, stream>>>(counts, rowptr, A);
    csr_fill<<<gridE, BLK, 0, stream>>>(nl, rowptr, counts, cart, shifts, geom, snb, E);
    gauss_k<<<gridE, BLK, 0, stream>>>(geom, snb, species, rs, inta, params, gauss, E);

    // ---- pass 0 ----
    atom_pass<false><<<A, 128, 0, stream>>>(geom, (const float*)gauss, snb, rowptr, nullptr, dens, A);
    // ---- pass 1 ----
    mlp_k<<<gridM, 256, 0, stream>>>(dens, w1_0, b1_0, w2_0, b2_0, outp, A);
    atom_pass<true><<<A, 128, 0, stream>>>(geom, (const float*)gauss, snb, rowptr, outp, dens, A);
    // ---- pass 2 (final -> d_out) ----
    mlp_k<<<gridM, 256, 0, stream>>>(dens, w1_1, b1_1, w2_1, b2_1, outp, A);
    atom_pass<true><<<A, 128, 0, stream>>>(geom, (const float*)gauss, snb, rowptr, outp, dout, A);
}